// Round 1
// baseline (33.426 us; speedup 1.0000x reference)
//
#include <hip/hip_runtime.h>
#include <math.h>

// TokenChoiceRouter: B=8, T=8192, D=512.
// d_out (float32, flat): [selected B*max_k][gate_weights B*max_k][raw_logits B*T][aux][z]
// max_k recovered host-side from out_size.

__global__ __launch_bounds__(256) void logits_kernel(
    const float* __restrict__ x, const float* __restrict__ W,
    float* __restrict__ logits, int n_tokens)
{
    const int gid  = blockIdx.x * blockDim.x + threadIdx.x;
    const int wave = gid >> 6;
    const int lane = threadIdx.x & 63;
    if (wave >= n_tokens) return;

    const float4* xp = reinterpret_cast<const float4*>(x + (size_t)wave * 512 + lane * 8);
    const float4* wp = reinterpret_cast<const float4*>(W + lane * 8);
    float4 x0 = xp[0]; float4 x1 = xp[1];
    float4 w0 = wp[0]; float4 w1 = wp[1];

    // Double accumulation: keeps logit sign decisions aligned with the f64
    // numpy reference (mask/count robustness); cost is hidden under HBM reads.
    double acc = (double)x0.x * w0.x + (double)x0.y * w0.y
               + (double)x0.z * w0.z + (double)x0.w * w0.w
               + (double)x1.x * w1.x + (double)x1.y * w1.y
               + (double)x1.z * w1.z + (double)x1.w * w1.w;

    #pragma unroll
    for (int off = 32; off > 0; off >>= 1)
        acc += __shfl_xor(acc, off, 64);

    if (lane == 0) logits[wave] = (float)acc;
}

__global__ __launch_bounds__(1024) void rowproc_kernel(
    const float* __restrict__ logits,
    float* __restrict__ out_sel, float* __restrict__ out_gw,
    float* __restrict__ ws_z, float* __restrict__ ws_sig,
    int T, int max_k)
{
    const int b    = blockIdx.x;
    const int tid  = threadIdx.x;
    const int lane = tid & 63;
    const int wid  = tid >> 6;          // 0..15
    const float* row = logits + (size_t)b * T;

    __shared__ float          s_log[8192];
    __shared__ unsigned short s_sel[8192];
    __shared__ float s_wredA[16];
    __shared__ float s_wredB[16];
    __shared__ int   s_wcnt[16];
    __shared__ int   s_woff[17];
    __shared__ float s_bmax, s_bsum, s_bsig;

    // Load 8 contiguous logits per thread (t = tid*8 + i).
    const int t0 = tid * 8;
    float v[8];
    float4 a0 = *reinterpret_cast<const float4*>(row + t0);
    float4 a1 = *reinterpret_cast<const float4*>(row + t0 + 4);
    v[0]=a0.x; v[1]=a0.y; v[2]=a0.z; v[3]=a0.w;
    v[4]=a1.x; v[5]=a1.y; v[6]=a1.z; v[7]=a1.w;
    #pragma unroll
    for (int i = 0; i < 8; ++i) s_log[t0 + i] = v[i];

    // ---- block max (for logsumexp) ----
    float m = v[0];
    #pragma unroll
    for (int i = 1; i < 8; ++i) m = fmaxf(m, v[i]);
    #pragma unroll
    for (int off = 32; off > 0; off >>= 1) m = fmaxf(m, __shfl_xor(m, off, 64));
    if (lane == 0) s_wredA[wid] = m;
    __syncthreads();
    if (tid == 0) {
        float mm = s_wredA[0];
        for (int i = 1; i < 16; ++i) mm = fmaxf(mm, s_wredA[i]);
        s_bmax = mm;
    }
    __syncthreads();
    const float bmax = s_bmax;

    // ---- sumexp, sigmoid-sum, local count ----
    float se = 0.f, sg = 0.f;
    int c_local = 0;
    #pragma unroll
    for (int i = 0; i < 8; ++i) {
        se += expf(v[i] - bmax);
        sg += 1.f / (1.f + expf(-v[i]));
        c_local += (v[i] >= 0.f) ? 1 : 0;
    }
    #pragma unroll
    for (int off = 32; off > 0; off >>= 1) {
        se += __shfl_xor(se, off, 64);
        sg += __shfl_xor(sg, off, 64);
    }
    if (lane == 0) { s_wredA[wid] = se; s_wredB[wid] = sg; }

    // ---- stable prefix scan of per-thread counts ----
    int inc = c_local;
    #pragma unroll
    for (int off = 1; off < 64; off <<= 1) {
        int n = __shfl_up(inc, off, 64);
        if (lane >= off) inc += n;
    }
    if (lane == 63) s_wcnt[wid] = inc;   // wave total
    __syncthreads();
    if (tid == 0) {
        int run = 0;
        for (int i = 0; i < 16; ++i) { s_woff[i] = run; run += s_wcnt[i]; }
        s_woff[16] = run;
        float A = 0.f, Bs = 0.f;
        for (int i = 0; i < 16; ++i) { A += s_wredA[i]; Bs += s_wredB[i]; }
        s_bsum = A; s_bsig = Bs;
    }
    __syncthreads();

    const int excl = s_woff[wid] + (inc - c_local);
    const int cnt  = s_woff[16];

    // Stable compaction: selected token indices in increasing t order.
    int o = excl;
    #pragma unroll
    for (int i = 0; i < 8; ++i) {
        if (v[i] >= 0.f) s_sel[o++] = (unsigned short)(t0 + i);
    }
    __syncthreads();

    // ---- fill outputs: idx[k] = sel[min(k, cnt-1)], cnt==0 -> token 0 ----
    for (int k = tid; k < max_k; k += 1024) {
        int id = (k < cnt) ? (int)s_sel[k]
                           : (cnt > 0 ? (int)s_sel[cnt - 1] : 0);
        out_sel[(size_t)b * max_k + k] = (float)id;   // index as float32
        float lg = s_log[id];
        out_gw [(size_t)b * max_k + k] = 1.f / (1.f + expf(-lg));
    }

    if (tid == 0) {
        ws_z  [b] = bmax + logf(s_bsum);   // logsumexp over row
        ws_sig[b] = s_bsig;                // sum of sigmoids over row
    }
}

__global__ void finalize_kernel(const float* __restrict__ ws_z,
                                const float* __restrict__ ws_sig,
                                float* __restrict__ out_aux,
                                float* __restrict__ out_z,
                                int B, float inv_BT)
{
    if (threadIdx.x == 0 && blockIdx.x == 0) {
        float s = 0.f, zz = 0.f;
        for (int b = 0; b < B; ++b) {
            s  += ws_sig[b];
            zz += ws_z[b] * ws_z[b];
        }
        float m = s * inv_BT;
        *out_aux = 0.01f  * m * (1.f - m);
        *out_z   = 0.001f * zz / (float)B;
    }
}

extern "C" void kernel_launch(void* const* d_in, const int* in_sizes, int n_in,
                              void* d_out, int out_size, void* d_ws, size_t ws_size,
                              hipStream_t stream)
{
    const float* x = (const float*)d_in[0];
    const float* W = (const float*)d_in[1];

    const int D  = in_sizes[1];          // 512
    const int BT = in_sizes[0] / D;      // 65536
    const int B  = 8;
    const int T  = BT / B;               // 8192
    const int max_k = (out_size - BT - 2) / (2 * B);

    float* out        = (float*)d_out;
    float* out_sel    = out;
    float* out_gw     = out + (size_t)B * max_k;
    float* out_logits = out + (size_t)2 * B * max_k;
    float* out_aux    = out + (size_t)2 * B * max_k + BT;
    float* out_z      = out_aux + 1;

    float* ws_z   = (float*)d_ws;
    float* ws_sig = ws_z + B;

    // K1: one wave per token, coalesced 2KB/wave reads of x.
    const int waves_per_block = 4;                 // 256 threads
    const int grid1 = (BT + waves_per_block - 1) / waves_per_block;
    logits_kernel<<<grid1, 256, 0, stream>>>(x, W, out_logits, BT);

    // K2: one block per batch row — logsumexp, sigmoid sum, compaction, fill.
    rowproc_kernel<<<B, 1024, 0, stream>>>(out_logits, out_sel, out_gw,
                                           ws_z, ws_sig, T, max_k);

    // K3: scalars.
    finalize_kernel<<<1, 64, 0, stream>>>(ws_z, ws_sig, out_aux, out_z,
                                          B, 1.0f / (float)BT);
}